// Round 9
// baseline (423.269 us; speedup 1.0000x reference)
//
#include <hip/hip_runtime.h>
#include <hip/hip_cooperative_groups.h>
#include <math.h>

namespace cg = cooperative_groups;

#define LN_EPS 1e-5f

typedef _Float16 h2v __attribute__((ext_vector_type(2)));

__device__ __forceinline__ float dot4(float4 a, float4 b) {
    return a.x*b.x + a.y*b.y + a.z*b.z + a.w*b.w;
}
__device__ __forceinline__ void fma4(float4& a, float s, float4 v) {
    a.x += s*v.x; a.y += s*v.y; a.z += s*v.z; a.w += s*v.w;
}
__device__ __forceinline__ float fast_rcp(float x) {
    return __builtin_amdgcn_rcpf(x);
}
__device__ __forceinline__ float fast_sigmoid(float x) {
    return fast_rcp(1.f + __expf(-x));
}
__device__ __forceinline__ float fast_tanh(float x) {
    return 1.f - 2.f*fast_rcp(__expf(2.f*x) + 1.f);
}
__device__ __forceinline__ float fdot2u(unsigned int a, unsigned int b, float c) {
#if __has_builtin(__builtin_amdgcn_fdot2)
    return __builtin_amdgcn_fdot2(__builtin_bit_cast(h2v, a),
                                  __builtin_bit_cast(h2v, b), c, false);
#else
    const h2v av = __builtin_bit_cast(h2v, a);
    const h2v bv = __builtin_bit_cast(h2v, b);
    return c + (float)av[0]*(float)bv[0] + (float)av[1]*(float)bv[1];
#endif
}
__device__ __forceinline__ float wsum64(float v) {
    #pragma unroll
    for (int off = 32; off > 0; off >>= 1) v += __shfl_xor(v, off);
    return v;
}

struct KP {
    const float *input, *mask, *timesteps, *pw, *pb, *lw, *lb;
    const float *q_w, *q_b, *q_g, *q_be, *k_w, *k_b, *k_g, *k_be;
    const float *attn_g, *attn_b, *out_w, *out_b, *out_g, *out_be;
    const float *wih, *whh, *bih, *bhh;
    const float *c1w, *c1b, *c2w, *c2b, *c3w, *c3b;
    float *qs, *kT, *gi;
    float2 *xm;
    float *out;
};

// ===========================================================================
// ONE cooperative kernel: 256 blocks x 512 threads, 1 block/CU (101KB LDS).
// Phase 1: embed + Q/K proj + LN (+ xm transpose)   [280 units]
// Phase 2: attention (d-split scores) + fused gi    [block = (b, 4 qi)]
// Phase 3: GRU + classifier                         [blocks 0..7]
// grid.sync() between phases replaces 3 kernel boundaries.
// ===========================================================================
__global__ void __launch_bounds__(512) k_fused(KP p)
{
    __shared__ __align__(16) unsigned int lds[25344];   // 101376 B
    const int blk = blockIdx.x;
    const int tid = threadIdx.x;
    cg::grid_group grid = cg::this_grid();

    // ======================= PHASE 1: embed/proj/xm =======================
    {
        const int sg = tid >> 7;          // sub-group 0..3 (4 rows each)
        const int t1 = tid & 127;
        float*  e_    = (float*)lds;                      // [4][4][128]
        float4* red4  = (float4*)((char*)lds + 8192);     // [4][128]
        float*  proj_ = (float*)((char*)lds + 16384);     // [4][4][128]
        float2* tile  = (float2*)lds;                     // [32][257] (xm)

        for (int u = blk; u < 280; u += 256) {
            if (u < 264) {
                const bool isq = (u >= 256);
                const int base = (isq ? (u - 256) : u) * 16 + sg * 4;
                float tv[4];
                #pragma unroll
                for (int r = 0; r < 4; ++r)
                    tv[r] = isq ? (float)(base + r) * (1.0f/127.0f)
                                : p.timesteps[base + r];
                float pwj = 0.f, pbj = 0.f;
                if (t1 > 0) { pwj = p.pw[t1-1]; pbj = p.pb[t1-1]; }
                const float lw0 = p.lw[0], lb0 = p.lb[0];
                #pragma unroll
                for (int r = 0; r < 4; ++r)
                    e_[(sg*4 + r)*128 + t1] =
                        (t1 == 0) ? (tv[r]*lw0 + lb0) : sinf(tv[r]*pwj + pbj);
                __syncthreads();

                const float* W  = isq ? p.q_w  : p.k_w;
                const float* Bv = isq ? p.q_b  : p.k_b;
                const float* G  = isq ? p.q_g  : p.k_g;
                const float* Be = isq ? p.q_be : p.k_be;

                {
                    const int jj = t1 >> 2, dc = t1 & 3;
                    const float4* e0 = (const float4*)(e_ + (sg*4+0)*128);
                    const float4* e1 = (const float4*)(e_ + (sg*4+1)*128);
                    const float4* e2 = (const float4*)(e_ + (sg*4+2)*128);
                    const float4* e3 = (const float4*)(e_ + (sg*4+3)*128);
                    #pragma unroll
                    for (int jb = 0; jb < 4; ++jb) {
                        const int j = jb*32 + jj;
                        const float4* wrow = (const float4*)(W + (size_t)j*128);
                        float a0=0.f, a1=0.f, a2=0.f, a3=0.f;
                        #pragma unroll
                        for (int k = 0; k < 8; ++k) {
                            const int idx = dc + 4*k;
                            const float4 w4 = wrow[idx];
                            a0 += dot4(w4, e0[idx]);
                            a1 += dot4(w4, e1[idx]);
                            a2 += dot4(w4, e2[idx]);
                            a3 += dot4(w4, e3[idx]);
                        }
                        a0 += __shfl_xor(a0, 1, 4); a0 += __shfl_xor(a0, 2, 4);
                        a1 += __shfl_xor(a1, 1, 4); a1 += __shfl_xor(a1, 2, 4);
                        a2 += __shfl_xor(a2, 1, 4); a2 += __shfl_xor(a2, 2, 4);
                        a3 += __shfl_xor(a3, 1, 4); a3 += __shfl_xor(a3, 2, 4);
                        if (dc == 0) {
                            const float bj = Bv[j];
                            proj_[(sg*4+0)*128 + j] = a0 + bj;
                            proj_[(sg*4+1)*128 + j] = a1 + bj;
                            proj_[(sg*4+2)*128 + j] = a2 + bj;
                            proj_[(sg*4+3)*128 + j] = a3 + bj;
                        }
                    }
                }
                __syncthreads();

                float acc[4];
                #pragma unroll
                for (int r = 0; r < 4; ++r) acc[r] = proj_[(sg*4+r)*128 + t1];

                red4[sg*128 + t1] = make_float4(acc[0], acc[1], acc[2], acc[3]);
                __syncthreads();
                for (int s = 64; s > 0; s >>= 1) {
                    if (t1 < s) {
                        float4 m = red4[sg*128 + t1];
                        const float4 o = red4[sg*128 + t1 + s];
                        m.x += o.x; m.y += o.y; m.z += o.z; m.w += o.w;
                        red4[sg*128 + t1] = m;
                    }
                    __syncthreads();
                }
                float4 mean = red4[sg*128];
                mean.x *= (1.0f/128.0f); mean.y *= (1.0f/128.0f);
                mean.z *= (1.0f/128.0f); mean.w *= (1.0f/128.0f);
                __syncthreads();
                const float d0 = acc[0]-mean.x, d1 = acc[1]-mean.y,
                            d2 = acc[2]-mean.z, d3 = acc[3]-mean.w;
                red4[sg*128 + t1] = make_float4(d0*d0, d1*d1, d2*d2, d3*d3);
                __syncthreads();
                for (int s = 64; s > 0; s >>= 1) {
                    if (t1 < s) {
                        float4 m = red4[sg*128 + t1];
                        const float4 o = red4[sg*128 + t1 + s];
                        m.x += o.x; m.y += o.y; m.z += o.z; m.w += o.w;
                        red4[sg*128 + t1] = m;
                    }
                    __syncthreads();
                }
                float4 var = red4[sg*128];
                var.x *= (1.0f/128.0f); var.y *= (1.0f/128.0f);
                var.z *= (1.0f/128.0f); var.w *= (1.0f/128.0f);

                const float gg = G[t1], bb = Be[t1];
                const float o0 = d0*rsqrtf(var.x+LN_EPS)*gg + bb;
                const float o1 = d1*rsqrtf(var.y+LN_EPS)*gg + bb;
                const float o2 = d2*rsqrtf(var.z+LN_EPS)*gg + bb;
                const float o3 = d3*rsqrtf(var.w+LN_EPS)*gg + bb;

                if (isq) {
                    const float sc = 0.08838834764831845f;   // 1/sqrt(128)
                    p.qs[(size_t)(base+0)*128 + t1] = o0*sc;
                    p.qs[(size_t)(base+1)*128 + t1] = o1*sc;
                    p.qs[(size_t)(base+2)*128 + t1] = o2*sc;
                    p.qs[(size_t)(base+3)*128 + t1] = o3*sc;
                } else {
                    const int b = base >> 9;
                    const int t = base & 511;
                    *(float4*)(p.kT + ((size_t)(b*128 + t1))*512 + t) =
                        make_float4(o0, o1, o2, o3);
                }
            } else {
                // ---- xm transpose unit ----
                const int idx = u - 264;
                const int b  = idx >> 1;
                const int t0 = (idx & 1) * 256;
                for (int k = tid; k < 8192; k += 512) {
                    const int c = k >> 8, t = k & 255;
                    const float m = p.mask [(size_t)(b*32 + c)*512 + t0 + t];
                    const float x = p.input[(size_t)(b*32 + c)*512 + t0 + t];
                    const float mm = 1.0f - m;
                    tile[c*257 + t] = make_float2(x*mm, mm);
                }
                __syncthreads();
                for (int k = tid; k < 8192; k += 512) {
                    const int t = k >> 5, c = k & 31;
                    p.xm[((size_t)b*512 + t0 + t)*32 + c] = tile[c*257 + t];
                }
            }
            __syncthreads();
        }
    }
    __threadfence();
    grid.sync();

    // ======================= PHASE 2: attn + gi =======================
    {
        const int b     = blk >> 5;
        const int qbase = (blk & 31) * 4;

        char* lmem = (char*)lds;
        float4* et4    = (float4*)lmem;                   // [512] (ql packed)
        float*  qshf   = (float*)(lmem + 8192);           // [4][128]
        float*  wshf   = (float*)(lmem + 10240);          // [128*66]
        float4* part4  = (float4*)(lmem + 44032);         // [4grp][4ql][128]
        float*  sAf    = (float*)(lmem + 76800);          // [4][16][32]
        float*  aAf    = (float*)(lmem + 84992);          // [4][16][32]
        float*  x2sf   = (float*)(lmem + 93184);          // [4][64]
        float*  rows4f = (float*)(lmem + 94208);          // [4][128]
        float*  redC   = (float*)(lmem + 96256);          // [8]
        float*  redD   = (float*)(lmem + 96288);          // [8]

        qshf[tid] = p.qs[(size_t)qbase*128 + tid];
        for (int idx = tid; idx < 8192; idx += 512)
            wshf[(idx >> 6)*66 + (idx & 63)] = p.out_w[idx];
        __syncthreads();

        // ---- scores, d-split: grp covers d in [grp*32, grp*32+32) ----
        {
            const int grp = tid >> 7;
            const int tl  = tid & 127;
            const float4* kp  = (const float4*)p.kT
                                + ((size_t)(b*128 + grp*32))*128 + tl;
            const float4* q0 = (const float4*)(qshf +   0) + grp*8;
            const float4* q1 = (const float4*)(qshf + 128) + grp*8;
            const float4* q2 = (const float4*)(qshf + 256) + grp*8;
            const float4* q3 = (const float4*)(qshf + 384) + grp*8;
            float4 a0 = make_float4(0,0,0,0), a1 = a0, a2 = a0, a3 = a0;
            float4 c0 = kp[0], c1 = kp[128], c2 = kp[256], c3 = kp[384];
            for (int c = 0; c < 8; ++c) {
                float4 n0, n1, n2, n3;
                if (c < 7) {
                    const float4* kn = kp + (size_t)(4*c+4)*128;
                    n0 = kn[0]; n1 = kn[128]; n2 = kn[256]; n3 = kn[384];
                }
                const float4 qa = q0[c], qb = q1[c], qc = q2[c], qd = q3[c];
                fma4(a0, qa.x, c0); fma4(a1, qb.x, c0); fma4(a2, qc.x, c0); fma4(a3, qd.x, c0);
                fma4(a0, qa.y, c1); fma4(a1, qb.y, c1); fma4(a2, qc.y, c1); fma4(a3, qd.y, c1);
                fma4(a0, qa.z, c2); fma4(a1, qb.z, c2); fma4(a2, qc.z, c2); fma4(a3, qd.z, c2);
                fma4(a0, qa.w, c3); fma4(a1, qb.w, c3); fma4(a2, qc.w, c3); fma4(a3, qd.w, c3);
                c0 = n0; c1 = n1; c2 = n2; c3 = n3;
            }
            part4[(grp*4 + 0)*128 + tl] = a0;
            part4[(grp*4 + 1)*128 + tl] = a1;
            part4[(grp*4 + 2)*128 + tl] = a2;
            part4[(grp*4 + 3)*128 + tl] = a3;
        }
        __syncthreads();

        // ---- combine partials + exp: thread owns one t ----
        {
            const int t = tid;
            const int tl4 = t >> 2, cm = t & 3;
            const float* pf = (const float*)part4;
            float v[4];
            #pragma unroll
            for (int ql = 0; ql < 4; ++ql) {
                float s = 0.f;
                #pragma unroll
                for (int g = 0; g < 4; ++g)
                    s += pf[((g*4 + ql)*128 + tl4)*4 + cm];
                v[ql] = __expf(s);
            }
            et4[t] = make_float4(v[0], v[1], v[2], v[3]);
        }
        __syncthreads();

        // ---- masked scan: c = tid&31, seg = tid>>5 (32 t each) ----
        {
            const int c   = tid & 31;
            const int seg = tid >> 5;
            const float2* xp = p.xm + ((size_t)b*512 + seg*32)*32 + c;
            float s0=0,s1=0,s2=0,s3=0, a0=0,a1=0,a2=0,a3=0;
            #pragma unroll 4
            for (int i = 0; i < 32; ++i) {
                const float2 v = xp[(size_t)i*32];
                const float4 e = et4[seg*32 + i];
                const float w0 = e.x*v.y, w1 = e.y*v.y, w2 = e.z*v.y, w3 = e.w*v.y;
                s0 += w0; s1 += w1; s2 += w2; s3 += w3;
                a0 += w0*v.x; a1 += w1*v.x; a2 += w2*v.x; a3 += w3*v.x;
            }
            sAf[(0*16 + seg)*32 + c] = s0; aAf[(0*16 + seg)*32 + c] = a0;
            sAf[(1*16 + seg)*32 + c] = s1; aAf[(1*16 + seg)*32 + c] = a1;
            sAf[(2*16 + seg)*32 + c] = s2; aAf[(2*16 + seg)*32 + c] = a2;
            sAf[(3*16 + seg)*32 + c] = s3; aAf[(3*16 + seg)*32 + c] = a3;
        }
        __syncthreads();

        // ---- attv + LN64 (first 4 waves, wave = one ql) ----
        if (tid < 256) {
            const int ql = tid >> 6;
            const int c2 = tid & 63;
            const int cc = c2 & 31;
            float ss = 0.f;
            #pragma unroll
            for (int g = 0; g < 16; ++g) ss += sAf[(ql*16 + g)*32 + cc];
            float attv;
            if (c2 < 32) {
                float aa = 0.f;
                #pragma unroll
                for (int g = 0; g < 16; ++g) aa += aAf[(ql*16 + g)*32 + cc];
                attv = (ss > 0.f) ? aa/ss : 0.f;
            } else {
                attv = (ss > 0.f) ? 1.0f : 0.0f;   // x == unmask indicator
            }
            const float mean = wsum64(attv) * (1.0f/64.0f);
            const float dv = attv - mean;
            const float var = wsum64(dv*dv) * (1.0f/64.0f);
            x2sf[ql*64 + c2] = dv*rsqrtf(var+LN_EPS)*p.attn_g[c2] + p.attn_b[c2];
        }
        __syncthreads();

        // ---- out linear + LN128 (sub-group = one ql) ----
        {
            const int ql = tid >> 7;
            const int j  = tid & 127;
            const int w  = tid >> 6;
            float acc = p.out_b[j];
            const float4* wrow = (const float4*)(wshf + j*66);
            const float4* xr   = (const float4*)(x2sf + ql*64);
            #pragma unroll
            for (int k = 0; k < 16; ++k) acc += dot4(wrow[k], xr[k]);

            float v = wsum64(acc);
            if ((tid & 63) == 0) redC[w] = v;
            __syncthreads();
            const float mean = (redC[ql*2] + redC[ql*2+1]) * (1.0f/128.0f);
            const float d = acc - mean;
            v = wsum64(d*d);
            if ((tid & 63) == 0) redD[w] = v;
            __syncthreads();
            const float var = (redD[ql*2] + redD[ql*2+1]) * (1.0f/128.0f);
            rows4f[ql*128 + j] =
                d*rsqrtf(var+LN_EPS)*p.out_g[j] + p.out_be[j];
        }
        __syncthreads();

        // ---- fused gi for this block's 4 (b, qi) rows ----
        {
            const float4* rows44 = (const float4*)rows4f;
            const int dc = tid & 3;
            #pragma unroll
            for (int pass = 0; pass < 3; ++pass) {
                const int g = pass*128 + (tid >> 2);
                const float4* wrow = (const float4*)(p.wih + (size_t)g*128);
                float ac0=0.f, ac1=0.f, ac2=0.f, ac3=0.f;
                #pragma unroll
                for (int k = 0; k < 8; ++k) {
                    const int idx = dc + 4*k;
                    const float4 w4 = wrow[idx];
                    ac0 += dot4(w4, rows44[0*32 + idx]);
                    ac1 += dot4(w4, rows44[1*32 + idx]);
                    ac2 += dot4(w4, rows44[2*32 + idx]);
                    ac3 += dot4(w4, rows44[3*32 + idx]);
                }
                ac0 += __shfl_xor(ac0, 1, 4); ac0 += __shfl_xor(ac0, 2, 4);
                ac1 += __shfl_xor(ac1, 1, 4); ac1 += __shfl_xor(ac1, 2, 4);
                ac2 += __shfl_xor(ac2, 1, 4); ac2 += __shfl_xor(ac2, 2, 4);
                ac3 += __shfl_xor(ac3, 1, 4); ac3 += __shfl_xor(ac3, 2, 4);
                if (dc == 0) {
                    const float bg = p.bih[g];
                    p.gi[((size_t)(qbase+0)*8 + b)*384 + g] = ac0 + bg;
                    p.gi[((size_t)(qbase+1)*8 + b)*384 + g] = ac1 + bg;
                    p.gi[((size_t)(qbase+2)*8 + b)*384 + g] = ac2 + bg;
                    p.gi[((size_t)(qbase+3)*8 + b)*384 + g] = ac3 + bg;
                }
            }
        }
    }
    __threadfence();
    grid.sync();

    if (blk >= 8) return;

    // ======================= PHASE 3: GRU + classifier =======================
    {
        const int b = blk;
        const int s = tid >> 7;                    // k-slice 0..3
        const int u = tid & 127;                   // unit

        unsigned int* hP = lds;                    // 64 uints (h fp16 pairs)
        float4* partg = (float4*)&lds[64];         // 3*128 float4
        float*  hcls  = (float*)&lds[64 + 1536];   // 128 floats

        // stage whh -> fp16 pairs in LDS (coalesced)
        {
            const float4* w4 = (const float4*)p.whh;   // 12288 float4
            #pragma unroll 4
            for (int k = 0; k < 24; ++k) {
                const int idx = tid + k*512;
                const float4 v = w4[idx];
                const int row = idx >> 5, c4 = idx & 31;
                h2v p0; p0[0] = (_Float16)v.x; p0[1] = (_Float16)v.y;
                h2v p1; p1[0] = (_Float16)v.z; p1[1] = (_Float16)v.w;
                lds[row*66 + c4*2    ] = __builtin_bit_cast(unsigned int, p0);
                lds[row*66 + c4*2 + 1] = __builtin_bit_cast(unsigned int, p1);
            }
        }
        __syncthreads();

        // my 48 weight pairs -> registers (aliased region: cannot be sunk)
        unsigned int wreg[3][16];
        #pragma unroll
        for (int g = 0; g < 3; ++g) {
            const uint2* src = (const uint2*)&lds[(g*128 + u)*66 + 16*s];
            #pragma unroll
            for (int i = 0; i < 8; ++i) {
                const uint2 t = src[i];
                wreg[g][2*i] = t.x; wreg[g][2*i+1] = t.y;
            }
        }
        __syncthreads();

        const float* gbase = p.gi + (size_t)b*384;
        float bh_r=0.f, bh_z=0.f, bh_n=0.f, gr0=0.f, gz0=0.f, gn0=0.f, hprev=0.f;
        if (tid < 64) hP[tid] = 0u;
        if (s == 0) {
            bh_r = p.bhh[u]; bh_z = p.bhh[u+128]; bh_n = p.bhh[u+256];
            gr0 = gbase[u]; gz0 = gbase[u+128]; gn0 = gbase[u+256];
        }
        __syncthreads();

        for (int qi = 0; qi < 128; ++qi) {
            const uint4* hp4 = (const uint4*)hP + s*4;
            float ar = 0.f, az = 0.f, an = 0.f;
            #pragma unroll
            for (int i = 0; i < 4; ++i) {
                const uint4 hv = hp4[i];
                ar = fdot2u(wreg[0][4*i+0], hv.x, ar);
                ar = fdot2u(wreg[0][4*i+1], hv.y, ar);
                ar = fdot2u(wreg[0][4*i+2], hv.z, ar);
                ar = fdot2u(wreg[0][4*i+3], hv.w, ar);
                az = fdot2u(wreg[1][4*i+0], hv.x, az);
                az = fdot2u(wreg[1][4*i+1], hv.y, az);
                az = fdot2u(wreg[1][4*i+2], hv.z, az);
                az = fdot2u(wreg[1][4*i+3], hv.w, az);
                an = fdot2u(wreg[2][4*i+0], hv.x, an);
                an = fdot2u(wreg[2][4*i+1], hv.y, an);
                an = fdot2u(wreg[2][4*i+2], hv.z, an);
                an = fdot2u(wreg[2][4*i+3], hv.w, an);
            }
            if (s > 0) partg[(s-1)*128 + u] = make_float4(ar, az, an, 0.f);

            float grn=0.f, gzn=0.f, gnn=0.f;
            if (s == 0 && qi < 127) {
                const float* gb = gbase + (size_t)(qi+1)*3072;
                grn = gb[u]; gzn = gb[u+128]; gnn = gb[u+256];
            }
            __syncthreads();

            if (s == 0) {
                const float4 p0 = partg[u], p1 = partg[128+u], p2 = partg[256+u];
                const float ghr = ar + p0.x + p1.x + p2.x + bh_r;
                const float ghz = az + p0.y + p1.y + p2.y + bh_z;
                const float ghn = an + p0.z + p1.z + p2.z + bh_n;
                const float r = fast_sigmoid(gr0 + ghr);
                const float z = fast_sigmoid(gz0 + ghz);
                const float n = fast_tanh(gn0 + r*ghn);
                const float hn2 = (1.f - z)*n + z*hprev;
                hprev = hn2;
                gr0 = grn; gz0 = gzn; gn0 = gnn;
                const float other = __shfl_xor(hn2, 1);
                if ((u & 1) == 0) {
                    h2v hp; hp[0] = (_Float16)hn2; hp[1] = (_Float16)other;
                    hP[u >> 1] = __builtin_bit_cast(unsigned int, hp);
                }
            }
            __syncthreads();
        }

        // classifier MLP (fp32 h)
        float* scr = (float*)partg;
        if (s == 0) hcls[u] = hprev;
        __syncthreads();
        if (tid < 128) {
            float acc = p.c1b[u];
            const float4* wc = (const float4*)(p.c1w + (size_t)u*128);
            const float4* v  = (const float4*)hcls;
            #pragma unroll
            for (int d4 = 0; d4 < 32; ++d4) acc += dot4(wc[d4], v[d4]);
            scr[u] = fmaxf(acc, 0.f);
        }
        __syncthreads();
        if (tid < 128) {
            float acc = p.c2b[u];
            const float4* wc = (const float4*)(p.c2w + (size_t)u*128);
            const float4* v  = (const float4*)scr;
            #pragma unroll
            for (int d4 = 0; d4 < 32; ++d4) acc += dot4(wc[d4], v[d4]);
            scr[128 + u] = fmaxf(acc, 0.f);
        }
        __syncthreads();
        if (tid < 2) {
            float acc = p.c3b[tid];
            const float4* wc = (const float4*)(p.c3w + (size_t)tid*128);
            const float4* v  = (const float4*)(scr + 128);
            #pragma unroll
            for (int d4 = 0; d4 < 32; ++d4) acc += dot4(wc[d4], v[d4]);
            p.out[(size_t)b*2 + tid] = acc;
        }
    }
}

// ---------------------------------------------------------------------------
extern "C" void kernel_launch(void* const* d_in, const int* in_sizes, int n_in,
                              void* d_out, int out_size, void* d_ws, size_t ws_size,
                              hipStream_t stream)
{
    float* ws = (float*)d_ws;
    KP p;
    p.input     = (const float*)d_in[0];
    p.mask      = (const float*)d_in[1];
    p.timesteps = (const float*)d_in[2];
    p.pw        = (const float*)d_in[3];
    p.pb        = (const float*)d_in[4];
    p.lw        = (const float*)d_in[5];
    p.lb        = (const float*)d_in[6];
    p.q_w       = (const float*)d_in[7];
    p.q_b       = (const float*)d_in[8];
    p.q_g       = (const float*)d_in[9];
    p.q_be      = (const float*)d_in[10];
    p.k_w       = (const float*)d_in[11];
    p.k_b       = (const float*)d_in[12];
    p.k_g       = (const float*)d_in[13];
    p.k_be      = (const float*)d_in[14];
    p.attn_g    = (const float*)d_in[15];
    p.attn_b    = (const float*)d_in[16];
    p.out_w     = (const float*)d_in[17];
    p.out_b     = (const float*)d_in[18];
    p.out_g     = (const float*)d_in[19];
    p.out_be    = (const float*)d_in[20];
    p.wih       = (const float*)d_in[21];
    p.whh       = (const float*)d_in[22];
    p.bih       = (const float*)d_in[23];
    p.bhh       = (const float*)d_in[24];
    p.c1w       = (const float*)d_in[25];
    p.c1b       = (const float*)d_in[26];
    p.c2w       = (const float*)d_in[27];
    p.c2b       = (const float*)d_in[28];
    p.c3w       = (const float*)d_in[29];
    p.c3b       = (const float*)d_in[30];

    p.qs  = ws;                         // 128*128          = 16384
    p.kT  = ws + 16384;                 // 8*128*512        = 524288
    p.gi  = ws + 16384 + 524288;        // 128*8*384        = 393216
    p.xm  = (float2*)(ws + 16384 + 524288 + 393216);   // 8*512*32 float2
    p.out = (float*)d_out;

    void* args[] = { &p };
    hipLaunchCooperativeKernel((void*)k_fused, dim3(256), dim3(512),
                               args, 0, stream);
}

// Round 10
// 244.122 us; speedup vs baseline: 1.7338x; 1.7338x over previous
//
#include <hip/hip_runtime.h>
#include <math.h>

#define LN_EPS 1e-5f

typedef _Float16 h2v __attribute__((ext_vector_type(2)));

__device__ __forceinline__ float dot4(float4 a, float4 b) {
    return a.x*b.x + a.y*b.y + a.z*b.z + a.w*b.w;
}
__device__ __forceinline__ void fma4(float4& a, float s, float4 v) {
    a.x += s*v.x; a.y += s*v.y; a.z += s*v.z; a.w += s*v.w;
}
__device__ __forceinline__ float fast_rcp(float x) {
    return __builtin_amdgcn_rcpf(x);
}
__device__ __forceinline__ float fast_sigmoid(float x) {
    return fast_rcp(1.f + __expf(-x));
}
__device__ __forceinline__ float fast_tanh(float x) {
    return 1.f - 2.f*fast_rcp(__expf(2.f*x) + 1.f);
}
__device__ __forceinline__ float fdot2u(unsigned int a, unsigned int b, float c) {
#if __has_builtin(__builtin_amdgcn_fdot2)
    return __builtin_amdgcn_fdot2(__builtin_bit_cast(h2v, a),
                                  __builtin_bit_cast(h2v, b), c, false);
#else
    const h2v av = __builtin_bit_cast(h2v, a);
    const h2v bv = __builtin_bit_cast(h2v, b);
    return c + (float)av[0]*(float)bv[0] + (float)av[1]*(float)bv[1];
#endif
}
__device__ __forceinline__ float wsum64(float v) {
    #pragma unroll
    for (int off = 32; off > 0; off >>= 1) v += __shfl_xor(v, off);
    return v;
}

// ---------------------------------------------------------------------------
// Kernel 1: blocks 0..63 = xm transpose; 64..95 = query rows; 96..1119 = key
// rows -> kT[b][d][t].  (R8 version, proven ~fast.)
// ---------------------------------------------------------------------------
__global__ void k_embed_proj(
    const float* __restrict__ input, const float* __restrict__ mask,
    const float* __restrict__ timesteps,
    const float* __restrict__ pw, const float* __restrict__ pb,
    const float* __restrict__ lw, const float* __restrict__ lb,
    const float* __restrict__ q_w, const float* __restrict__ q_b,
    const float* __restrict__ q_g, const float* __restrict__ q_be,
    const float* __restrict__ k_w, const float* __restrict__ k_b,
    const float* __restrict__ k_g, const float* __restrict__ k_be,
    float* __restrict__ qs, float* __restrict__ kT, float2* __restrict__ xm)
{
    const int blk = blockIdx.x;
    const int tid = threadIdx.x;          // 0..127

    __shared__ __align__(16) float e[4][128];
    __shared__ __align__(16) float4 red[128];
    __shared__ __align__(16) float proj[4][128];
    __shared__ __align__(16) float2 tile[32][65];

    if (blk < 64) {
        const int b  = blk >> 3;
        const int t0 = (blk & 7) * 64;
        const int cg = tid >> 6;          // 0..1
        const int tt = tid & 63;
        #pragma unroll
        for (int c16 = 0; c16 < 16; ++c16) {
            const int c = c16*2 + cg;
            const float m = mask [(size_t)(b*32 + c)*512 + t0 + tt];
            const float x = input[(size_t)(b*32 + c)*512 + t0 + tt];
            const float mm = 1.0f - m;
            tile[c][tt] = make_float2(x*mm, mm);
        }
        __syncthreads();
        const int c2 = tid & 31;
        const int tg = tid >> 5;          // 0..3
        #pragma unroll
        for (int k = 0; k < 16; ++k) {
            const int t = tg*16 + k;
            xm[((size_t)b*512 + t0 + t)*32 + c2] = tile[c2][t];
        }
        return;
    }

    const bool isq = blk < 96;
    float tv[4];
    int kidx0 = 0;
    if (isq) {
        const int q0 = (blk - 64) * 4;
        #pragma unroll
        for (int r = 0; r < 4; ++r) tv[r] = (float)(q0 + r) * (1.0f/127.0f);
    } else {
        kidx0 = (blk - 96) * 4;
        #pragma unroll
        for (int r = 0; r < 4; ++r) tv[r] = timesteps[kidx0 + r];
    }

    float pwj = 0.f, pbj = 0.f;
    if (tid > 0) { pwj = pw[tid-1]; pbj = pb[tid-1]; }
    const float lw0 = lw[0], lb0 = lb[0];
    #pragma unroll
    for (int r = 0; r < 4; ++r)
        e[r][tid] = (tid == 0) ? (tv[r]*lw0 + lb0) : sinf(tv[r]*pwj + pbj);
    __syncthreads();

    const float* W  = isq ? q_w  : k_w;
    const float* Bv = isq ? q_b  : k_b;
    const float* G  = isq ? q_g  : k_g;
    const float* Be = isq ? q_be : k_be;

    {
        const int jj = tid >> 2, dc = tid & 3;
        const float4* e0 = (const float4*)(&e[0][0]);
        const float4* e1 = (const float4*)(&e[1][0]);
        const float4* e2 = (const float4*)(&e[2][0]);
        const float4* e3 = (const float4*)(&e[3][0]);
        #pragma unroll
        for (int jb = 0; jb < 4; ++jb) {
            const int j = jb*32 + jj;
            const float4* wrow = (const float4*)(W + (size_t)j*128);
            float a0=0.f, a1=0.f, a2=0.f, a3=0.f;
            #pragma unroll
            for (int k = 0; k < 8; ++k) {
                const int idx = dc + 4*k;
                const float4 w4 = wrow[idx];
                a0 += dot4(w4, e0[idx]);
                a1 += dot4(w4, e1[idx]);
                a2 += dot4(w4, e2[idx]);
                a3 += dot4(w4, e3[idx]);
            }
            a0 += __shfl_xor(a0, 1, 4); a0 += __shfl_xor(a0, 2, 4);
            a1 += __shfl_xor(a1, 1, 4); a1 += __shfl_xor(a1, 2, 4);
            a2 += __shfl_xor(a2, 1, 4); a2 += __shfl_xor(a2, 2, 4);
            a3 += __shfl_xor(a3, 1, 4); a3 += __shfl_xor(a3, 2, 4);
            if (dc == 0) {
                const float bj = Bv[j];
                proj[0][j] = a0 + bj; proj[1][j] = a1 + bj;
                proj[2][j] = a2 + bj; proj[3][j] = a3 + bj;
            }
        }
    }
    __syncthreads();

    float acc[4];
    #pragma unroll
    for (int r = 0; r < 4; ++r) acc[r] = proj[r][tid];

    red[tid] = make_float4(acc[0], acc[1], acc[2], acc[3]);
    __syncthreads();
    for (int s = 64; s > 0; s >>= 1) {
        if (tid < s) {
            float4 m = red[tid]; const float4 o = red[tid+s];
            m.x += o.x; m.y += o.y; m.z += o.z; m.w += o.w;
            red[tid] = m;
        }
        __syncthreads();
    }
    float4 mean = red[0];
    mean.x *= (1.0f/128.0f); mean.y *= (1.0f/128.0f);
    mean.z *= (1.0f/128.0f); mean.w *= (1.0f/128.0f);
    __syncthreads();
    const float d0 = acc[0]-mean.x, d1 = acc[1]-mean.y,
                d2 = acc[2]-mean.z, d3 = acc[3]-mean.w;
    red[tid] = make_float4(d0*d0, d1*d1, d2*d2, d3*d3);
    __syncthreads();
    for (int s = 64; s > 0; s >>= 1) {
        if (tid < s) {
            float4 m = red[tid]; const float4 o = red[tid+s];
            m.x += o.x; m.y += o.y; m.z += o.z; m.w += o.w;
            red[tid] = m;
        }
        __syncthreads();
    }
    float4 var = red[0];
    var.x *= (1.0f/128.0f); var.y *= (1.0f/128.0f);
    var.z *= (1.0f/128.0f); var.w *= (1.0f/128.0f);

    const float gg = G[tid], bb = Be[tid];
    const float o0 = d0*rsqrtf(var.x+LN_EPS)*gg + bb;
    const float o1 = d1*rsqrtf(var.y+LN_EPS)*gg + bb;
    const float o2 = d2*rsqrtf(var.z+LN_EPS)*gg + bb;
    const float o3 = d3*rsqrtf(var.w+LN_EPS)*gg + bb;

    if (isq) {
        const float sc = 0.08838834764831845f;   // 1/sqrt(128)
        const int q0 = (blk - 64)*4;
        qs[(size_t)(q0+0)*128 + tid] = o0*sc;
        qs[(size_t)(q0+1)*128 + tid] = o1*sc;
        qs[(size_t)(q0+2)*128 + tid] = o2*sc;
        qs[(size_t)(q0+3)*128 + tid] = o3*sc;
    } else {
        const int b = kidx0 >> 9;
        const int t = kidx0 & 511;
        *(float4*)(kT + ((size_t)(b*128 + tid))*512 + t) =
            make_float4(o0, o1, o2, o3);
    }
}

// ---------------------------------------------------------------------------
// Kernel 2: attention. 256 blocks = (b, 4 qi), 256 threads.  (R8 version.)
// ---------------------------------------------------------------------------
__global__ void __launch_bounds__(256) k_attn(
    const float2* __restrict__ xm,
    const float* __restrict__ qs, const float* __restrict__ kT,
    const float* __restrict__ attn_g, const float* __restrict__ attn_b,
    const float* __restrict__ out_w, const float* __restrict__ out_b,
    const float* __restrict__ out_g, const float* __restrict__ out_be,
    float* __restrict__ outm)
{
    const int b     = blockIdx.x >> 5;
    const int qbase = (blockIdx.x & 31) * 4;
    const int tid   = threadIdx.x;          // 0..255

    __shared__ __align__(16) float et[4][512];
    __shared__ __align__(16) float qsh[4][128];
    __shared__ __align__(16) float wsh[128*66];
    __shared__ __align__(16) float sA[4][8][32];
    __shared__ __align__(16) float aA[4][8][32];
    __shared__ __align__(16) float x2s[4][64];
    __shared__ float redC[4];

    for (int idx = tid; idx < 512; idx += 256)
        qsh[idx >> 7][idx & 127] = qs[(size_t)(qbase + (idx >> 7))*128 + (idx & 127)];
    for (int idx = tid; idx < 8192; idx += 256)
        wsh[(idx >> 6)*66 + (idx & 63)] = out_w[idx];
    __syncthreads();

    {
        const int grp = tid >> 7;
        const int tl  = tid & 127;
        const int q0  = grp*2;
        const float4* kp  = (const float4*)kT + (size_t)b*128*128 + tl;
        const float4* qa4 = (const float4*)qsh[q0];
        const float4* qb4 = (const float4*)qsh[q0+1];
        float4 a0 = make_float4(0,0,0,0), a1 = make_float4(0,0,0,0);
        float4 c0 = kp[0], c1 = kp[128], c2 = kp[256], c3 = kp[384];
        for (int c = 0; c < 32; ++c) {
            float4 n0, n1, n2, n3;
            if (c < 31) {
                const float4* kn = kp + (size_t)(4*c+4)*128;
                n0 = kn[0]; n1 = kn[128]; n2 = kn[256]; n3 = kn[384];
            }
            const float4 qa = qa4[c], qb = qb4[c];
            fma4(a0, qa.x, c0); fma4(a1, qb.x, c0);
            fma4(a0, qa.y, c1); fma4(a1, qb.y, c1);
            fma4(a0, qa.z, c2); fma4(a1, qb.z, c2);
            fma4(a0, qa.w, c3); fma4(a1, qb.w, c3);
            c0 = n0; c1 = n1; c2 = n2; c3 = n3;
        }
        a0.x = __expf(a0.x); a0.y = __expf(a0.y); a0.z = __expf(a0.z); a0.w = __expf(a0.w);
        a1.x = __expf(a1.x); a1.y = __expf(a1.y); a1.z = __expf(a1.z); a1.w = __expf(a1.w);
        ((float4*)et[q0])[tl]   = a0;
        ((float4*)et[q0+1])[tl] = a1;
    }
    __syncthreads();

    {
        const int c   = tid & 31;
        const int seg = tid >> 5;
        const float2* xp = xm + ((size_t)b*512 + seg*64)*32 + c;
        float s0=0,s1=0,s2=0,s3=0, a0=0,a1=0,a2=0,a3=0;
        #pragma unroll 4
        for (int i = 0; i < 64; ++i) {
            const float2 v = xp[(size_t)i*32];
            const int t = seg*64 + i;
            const float w0 = et[0][t]*v.y, w1 = et[1][t]*v.y;
            const float w2 = et[2][t]*v.y, w3 = et[3][t]*v.y;
            s0 += w0; s1 += w1; s2 += w2; s3 += w3;
            a0 += w0*v.x; a1 += w1*v.x; a2 += w2*v.x; a3 += w3*v.x;
        }
        sA[0][seg][c]=s0; sA[1][seg][c]=s1; sA[2][seg][c]=s2; sA[3][seg][c]=s3;
        aA[0][seg][c]=a0; aA[1][seg][c]=a1; aA[2][seg][c]=a2; aA[3][seg][c]=a3;
    }
    __syncthreads();

    {
        const int ql = tid >> 6;
        const int c2 = tid & 63;
        const int cc = c2 & 31;
        float ss = 0.f;
        #pragma unroll
        for (int g = 0; g < 8; ++g) ss += sA[ql][g][cc];
        float attv;
        if (c2 < 32) {
            float aa = 0.f;
            #pragma unroll
            for (int g = 0; g < 8; ++g) aa += aA[ql][g][cc];
            attv = (ss > 0.f) ? aa/ss : 0.f;
        } else {
            attv = (ss > 0.f) ? 1.0f : 0.0f;
        }
        const float mean = wsum64(attv) * (1.0f/64.0f);
        const float dv = attv - mean;
        const float var = wsum64(dv*dv) * (1.0f/64.0f);
        x2s[ql][c2] = dv*rsqrtf(var+LN_EPS)*attn_g[c2] + attn_b[c2];
    }
    __syncthreads();

    {
        const int jhalf = tid >> 7;
        const int j     = tid & 127;
        const int wave  = tid >> 6;
        for (int lq2 = 0; lq2 < 2; ++lq2) {
            const int ql = jhalf*2 + lq2;
            float acc = out_b[j];
            const float4* wrow = (const float4*)(wsh + j*66);
            const float4* xr   = (const float4*)x2s[ql];
            #pragma unroll
            for (int k = 0; k < 16; ++k) acc += dot4(wrow[k], xr[k]);

            float v = wsum64(acc);
            if ((tid & 63) == 0) redC[wave] = v;
            __syncthreads();
            const float mean = (redC[jhalf*2] + redC[jhalf*2+1]) * (1.0f/128.0f);
            __syncthreads();
            const float d = acc - mean;
            v = wsum64(d*d);
            if ((tid & 63) == 0) redC[wave] = v;
            __syncthreads();
            const float var = (redC[jhalf*2] + redC[jhalf*2+1]) * (1.0f/128.0f);
            outm[((size_t)b*128 + qbase + ql)*128 + j] =
                d*rsqrtf(var+LN_EPS)*out_g[j] + out_be[j];
            __syncthreads();
        }
    }
}

// ---------------------------------------------------------------------------
// Kernel 3: gi[qi][b][g] = outm[b,qi,:]·wih[g,:] + bih[g]  (R8 version.)
// ---------------------------------------------------------------------------
__global__ void k_gi(const float* __restrict__ outm,
                     const float* __restrict__ wih, const float* __restrict__ bih,
                     float* __restrict__ gi)
{
    const int qi  = blockIdx.x;
    const int tid = threadIdx.x;   // 0..383
    __shared__ __align__(16) float rows[8][128];
    for (int idx = tid; idx < 1024; idx += 384) {
        const int b = idx >> 7, d = idx & 127;
        rows[b][d] = outm[(size_t)(b*128+qi)*128 + d];
    }
    __syncthreads();

    const int g0 = tid >> 2, dc = tid & 3;
    #pragma unroll
    for (int gb = 0; gb < 4; ++gb) {
        const int g = gb*96 + g0;
        const float4* wrow = (const float4*)(wih + (size_t)g*128);
        float acc[8] = {0,0,0,0,0,0,0,0};
        #pragma unroll
        for (int k = 0; k < 8; ++k) {
            const int idx = dc + 4*k;
            const float4 w4 = wrow[idx];
            #pragma unroll
            for (int b = 0; b < 8; ++b)
                acc[b] += dot4(w4, ((const float4*)rows[b])[idx]);
        }
        #pragma unroll
        for (int b = 0; b < 8; ++b) {
            acc[b] += __shfl_xor(acc[b], 1, 4);
            acc[b] += __shfl_xor(acc[b], 2, 4);
        }
        if (dc == 0) {
            const float bi = bih[g];
            #pragma unroll
            for (int b = 0; b < 8; ++b)
                gi[((size_t)qi*8 + b)*384 + g] = acc[b] + bi;
        }
    }
}

// ---------------------------------------------------------------------------
// Kernel 4: GRU + fused classifier. 8 blocks x 512 threads.
// R8's LDS-alias pinned fp16 weights (VGPR=88, no spill) with a shorter
// serial path: 64 gate threads each own TWO adjacent units -> both gate
// chains in-thread (ILP), one packed b32 h-write, NO ds_permute (~120 cyc
// was on the critical path every step). All 4 slices write partials
// uniformly; gate threads read 8 consecutive float4s.
// ---------------------------------------------------------------------------
__global__ void __launch_bounds__(512) k_gru_cls(
    const float* __restrict__ gi,
    const float* __restrict__ whh, const float* __restrict__ bhh,
    const float* __restrict__ c1w, const float* __restrict__ c1b,
    const float* __restrict__ c2w, const float* __restrict__ c2b,
    const float* __restrict__ c3w, const float* __restrict__ c3b,
    float* __restrict__ out)
{
    const int b   = blockIdx.x;
    const int tid = threadIdx.x;                 // 0..511
    const int s   = tid >> 7;                    // k-slice 0..3
    const int u   = tid & 127;                   // unit (dot identity)

    __shared__ __align__(16) unsigned int lds[25344];
    unsigned int* hP = lds;                      // 64 uints (h fp16 pairs)
    float4* partg = (float4*)&lds[64];           // [4][128] float4
    float*  hcls  = (float*)&lds[64 + 2048];     // 128 floats

    // ---- stage whh -> fp16 pairs in LDS (coalesced) ----
    {
        const float4* w4 = (const float4*)whh;   // 12288 float4
        #pragma unroll 4
        for (int k = 0; k < 24; ++k) {
            const int idx = tid + k*512;
            const float4 v = w4[idx];
            const int row = idx >> 5, c4 = idx & 31;
            h2v p0; p0[0] = (_Float16)v.x; p0[1] = (_Float16)v.y;
            h2v p1; p1[0] = (_Float16)v.z; p1[1] = (_Float16)v.w;
            lds[row*66 + c4*2    ] = __builtin_bit_cast(unsigned int, p0);
            lds[row*66 + c4*2 + 1] = __builtin_bit_cast(unsigned int, p1);
        }
    }
    __syncthreads();

    // ---- my 48 weight pairs -> registers (aliased region: cannot be sunk) ----
    unsigned int wreg[3][16];
    #pragma unroll
    for (int g = 0; g < 3; ++g) {
        const uint2* src = (const uint2*)&lds[(g*128 + u)*66 + 16*s];
        #pragma unroll
        for (int i = 0; i < 8; ++i) {
            const uint2 t = src[i];
            wreg[g][2*i] = t.x; wreg[g][2*i+1] = t.y;
        }
    }
    __syncthreads();

    // ---- gate threads: tid 0..63, units 2t and 2t+1 ----
    const float* gbase = gi + (size_t)b*384;
    float bhrA=0.f,bhzA=0.f,bhnA=0.f, bhrB=0.f,bhzB=0.f,bhnB=0.f;
    float grA=0.f,gzA=0.f,gnA=0.f, grB=0.f,gzB=0.f,gnB=0.f;
    float hprevA=0.f, hprevB=0.f;
    const int t2 = tid << 1;                     // 2t (valid for tid<64)
    if (tid < 64) {
        bhrA = bhh[t2];     bhrB = bhh[t2+1];
        bhzA = bhh[t2+128]; bhzB = bhh[t2+129];
        bhnA = bhh[t2+256]; bhnB = bhh[t2+257];
        grA = gbase[t2];     grB = gbase[t2+1];
        gzA = gbase[t2+128]; gzB = gbase[t2+129];
        gnA = gbase[t2+256]; gnB = gbase[t2+257];
        hP[tid] = 0u;
    }
    __syncthreads();

    for (int qi = 0; qi < 128; ++qi) {
        const uint4* hp4 = (const uint4*)hP + s*4;
        float ar = 0.f, az = 0.f, an = 0.f;
        #pragma unroll
        for (int i = 0; i < 4; ++i) {
            const uint4 hv = hp4[i];
            ar = fdot2u(wreg[0][4*i+0], hv.x, ar);
            ar = fdot2u(wreg[0][4*i+1], hv.y, ar);
            ar = fdot2u(wreg[0][4*i+2], hv.z, ar);
            ar = fdot2u(wreg[0][4*i+3], hv.w, ar);
            az = fdot2u(wreg[1][4*i+0], hv.x, az);
            az = fdot2u(wreg[1][4*i+1], hv.y, az);
            az = fdot2u(wreg[1][4*i+2], hv.z, az);
            az = fdot2u(wreg[1][4*i+3], hv.w, az);
            an = fdot2u(wreg[2][4*i+0], hv.x, an);
            an = fdot2u(wreg[2][4*i+1], hv.y, an);
            an = fdot2u(wreg[2][4*i+2], hv.z, an);
            an = fdot2u(wreg[2][4*i+3], hv.w, an);
        }
        partg[s*128 + u] = make_float4(ar, az, an, 0.f);

        // prefetch next step's gi (6 values) while partials drain
        float grnA=0.f,gznA=0.f,gnnA=0.f, grnB=0.f,gznB=0.f,gnnB=0.f;
        if (tid < 64 && qi < 127) {
            const float* gb = gbase + (size_t)(qi+1)*3072;
            grnA = gb[t2];     grnB = gb[t2+1];
            gznA = gb[t2+128]; gznB = gb[t2+129];
            gnnA = gb[t2+256]; gnnB = gb[t2+257];
        }
        __syncthreads();

        if (tid < 64) {
            const float4 a0 = partg[t2],       a1 = partg[128+t2],
                         a2 = partg[256+t2],   a3 = partg[384+t2];
            const float4 b0 = partg[t2+1],     b1 = partg[129+t2],
                         b2 = partg[257+t2],   b3 = partg[385+t2];
            const float ghrA = a0.x+a1.x+a2.x+a3.x + bhrA;
            const float ghzA = a0.y+a1.y+a2.y+a3.y + bhzA;
            const float ghnA = a0.z+a1.z+a2.z+a3.z + bhnA;
            const float ghrB = b0.x+b1.x+b2.x+b3.x + bhrB;
            const float ghzB = b0.y+b1.y+b2.y+b3.y + bhzB;
            const float ghnB = b0.z+b1.z+b2.z+b3.z + bhnB;
            const float rA = fast_sigmoid(grA + ghrA);
            const float zA = fast_sigmoid(gzA + ghzA);
            const float nA = fast_tanh(gnA + rA*ghnA);
            const float rB = fast_sigmoid(grB + ghrB);
            const float zB = fast_sigmoid(gzB + ghzB);
            const float nB = fast_tanh(gnB + rB*ghnB);
            const float hA = (1.f - zA)*nA + zA*hprevA;
            const float hB = (1.f - zB)*nB + zB*hprevB;
            hprevA = hA; hprevB = hB;
            grA = grnA; gzA = gznA; gnA = gnnA;
            grB = grnB; gzB = gznB; gnB = gnnB;
            h2v hp; hp[0] = (_Float16)hA; hp[1] = (_Float16)hB;
            hP[tid] = __builtin_bit_cast(unsigned int, hp);
        }
        __syncthreads();
    }

    // ---- fused classifier MLP (fp32 h from registers) ----
    float* scr = (float*)partg;
    if (tid < 64) { hcls[t2] = hprevA; hcls[t2+1] = hprevB; }
    __syncthreads();
    if (tid < 128) {
        float acc = c1b[u];
        const float4* wc = (const float4*)(c1w + (size_t)u*128);
        const float4* v  = (const float4*)hcls;
        #pragma unroll
        for (int d4 = 0; d4 < 32; ++d4) acc += dot4(wc[d4], v[d4]);
        scr[u] = fmaxf(acc, 0.f);
    }
    __syncthreads();
    if (tid < 128) {
        float acc = c2b[u];
        const float4* wc = (const float4*)(c2w + (size_t)u*128);
        const float4* v  = (const float4*)scr;
        #pragma unroll
        for (int d4 = 0; d4 < 32; ++d4) acc += dot4(wc[d4], v[d4]);
        scr[128 + u] = fmaxf(acc, 0.f);
    }
    __syncthreads();
    if (tid < 2) {
        float acc = c3b[tid];
        const float4* wc = (const float4*)(c3w + (size_t)tid*128);
        const float4* v  = (const float4*)(scr + 128);
        #pragma unroll
        for (int d4 = 0; d4 < 32; ++d4) acc += dot4(wc[d4], v[d4]);
        out[(size_t)b*2 + tid] = acc;
    }
}

// ---------------------------------------------------------------------------
extern "C" void kernel_launch(void* const* d_in, const int* in_sizes, int n_in,
                              void* d_out, int out_size, void* d_ws, size_t ws_size,
                              hipStream_t stream)
{
    const float* input     = (const float*)d_in[0];
    const float* mask      = (const float*)d_in[1];
    const float* timesteps = (const float*)d_in[2];
    const float* pw        = (const float*)d_in[3];
    const float* pb        = (const float*)d_in[4];
    const float* lw        = (const float*)d_in[5];
    const float* lb        = (const float*)d_in[6];
    const float* q_w       = (const float*)d_in[7];
    const float* q_b       = (const float*)d_in[8];
    const float* q_g       = (const float*)d_in[9];
    const float* q_be      = (const float*)d_in[10];
    const float* k_w       = (const float*)d_in[11];
    const float* k_b       = (const float*)d_in[12];
    const float* k_g       = (const float*)d_in[13];
    const float* k_be      = (const float*)d_in[14];
    const float* attn_g    = (const float*)d_in[15];
    const float* attn_b    = (const float*)d_in[16];
    const float* out_w     = (const float*)d_in[17];
    const float* out_b     = (const float*)d_in[18];
    const float* out_g     = (const float*)d_in[19];
    const float* out_be    = (const float*)d_in[20];
    const float* gru_wih   = (const float*)d_in[21];
    const float* gru_whh   = (const float*)d_in[22];
    const float* gru_bih   = (const float*)d_in[23];
    const float* gru_bhh   = (const float*)d_in[24];
    const float* c1_w      = (const float*)d_in[25];
    const float* c1_b      = (const float*)d_in[26];
    const float* c2_w      = (const float*)d_in[27];
    const float* c2_b      = (const float*)d_in[28];
    const float* c3_w      = (const float*)d_in[29];
    const float* c3_b      = (const float*)d_in[30];

    float* ws   = (float*)d_ws;
    float*  qs   = ws;                    // 128*128             = 16384
    float*  kT   = qs   + 16384;          // 8*128*512           = 524288
    float*  outm = kT   + 524288;         // 8*128*128           = 131072
    float*  gi   = outm + 131072;         // 128*8*384           = 393216
    float2* xm   = (float2*)(gi + 393216);// 8*512*32 float2     = 262144 floats

    k_embed_proj<<<1120, 128, 0, stream>>>(input, mask, timesteps,
                                           pw, pb, lw, lb,
                                           q_w, q_b, q_g, q_be,
                                           k_w, k_b, k_g, k_be, qs, kT, xm);
    k_attn<<<256, 256, 0, stream>>>(xm, qs, kT,
                                    attn_g, attn_b, out_w, out_b,
                                    out_g, out_be, outm);
    k_gi<<<128, 384, 0, stream>>>(outm, gru_wih, gru_bih, gi);
    k_gru_cls<<<8, 512, 0, stream>>>(gi, gru_whh, gru_bhh,
                                     c1_w, c1_b, c2_w, c2_b, c3_w, c3_b,
                                     (float*)d_out);
}